// Round 1
// baseline (798.386 us; speedup 1.0000x reference)
//
#include <hip/hip_runtime.h>

// Problem constants
#define B_      64
#define CIN     32
#define H_      28
#define W_      28
#define K_      5
#define OH_     24
#define OW_     24
#define COUT    128
#define IN_SIZE (CIN * K_ * K_)   // 800

// Tiling
#define TH       8                      // output rows per tile
#define INROWS   (TH + K_ - 1)          // 12 input rows
#define TILE_POS (TH * OW_)             // 192 threads / block
#define NTILES   (OH_ / TH)             // 3
#define NT       8                      // trees per block
#define TGROUPS  (COUT / NT)            // 16
#define XTILE_FLOATS (CIN * INROWS * W_)  // 10752 (43008 B LDS)

// Workspace layout (bytes)
#define A1_BYTES  (COUT * 36 * 6 * 4)       // 110592: precomputed byte offsets into x tile
#define PL1_BYTES (COUT * 36 * 64 * 4)      // 1179648: (base,delta) pairs
#define PL2_BYTES (COUT * 6 * 64 * 4)       // 196608
#define PL3_BYTES (COUT * 1 * 64 * 4)       // 32768
#define WS_NEEDED (A1_BYTES + PL1_BYTES + PL2_BYTES + PL3_BYTES)

__device__ __forceinline__ float clamp01(float v) {
    return fminf(fmaxf(v, 0.0f), 1.0f);
}

// 6-D multilinear interpolation over 64 LUT entries via nested lerp.
// Weight index bit layout (from reference): x0 -> MSB(32), x5 -> LSB(1).
// Contract LSB-first: stage1 pairs differ in the x5 bit.
// PRE: pl holds (base, delta) interleaved; !PRE: pl holds raw lut values.
template<bool PRE>
__device__ __forceinline__ float contract64(const float* __restrict__ pl,
                                            float x0, float x1, float x2,
                                            float x3, float x4, float x5) {
    float v[32];
#pragma unroll
    for (int a = 0; a < 32; ++a) {
        float b = pl[2*a];
        float d = PRE ? pl[2*a+1] : (pl[2*a+1] - b);
        v[a] = fmaf(x5, d, b);
    }
#pragma unroll
    for (int a = 0; a < 16; ++a) v[a] = fmaf(x4, v[2*a+1] - v[2*a], v[2*a]);
#pragma unroll
    for (int a = 0; a < 8; ++a)  v[a] = fmaf(x3, v[2*a+1] - v[2*a], v[2*a]);
#pragma unroll
    for (int a = 0; a < 4; ++a)  v[a] = fmaf(x2, v[2*a+1] - v[2*a], v[2*a]);
#pragma unroll
    for (int a = 0; a < 2; ++a)  v[a] = fmaf(x1, v[2*a+1] - v[2*a], v[2*a]);
    return clamp01(fmaf(x0, v[1] - v[0], v[0]));
}

// Level-1 node: gather 6 x-values from LDS tile, interpolate.
// idx1: PRE -> precomputed byte offsets; !PRE -> raw map1 (decompose inline).
template<bool PRE>
__device__ __forceinline__ float eval_l1(int t, int n1,
                                         const int* __restrict__ idx1,
                                         const float* __restrict__ l1,
                                         const char* __restrict__ xsb,
                                         int laneoff) {
    const int base = (t * 36 + n1) * 6;
    int off[6];
#pragma unroll
    for (int j = 0; j < 6; ++j) {
        int m = idx1[base + j];
        if (PRE) {
            off[j] = m;
        } else {
            int c  = m / 25;
            int r  = m - 25 * c;
            int kh = r / 5;
            int kw = r - 5 * kh;
            off[j] = (c * (INROWS * W_) + kh * W_ + kw) * 4;
        }
        off[j] = __builtin_amdgcn_readfirstlane(off[j]);  // pin uniform -> SGPR
    }
    float xv[6];
#pragma unroll
    for (int j = 0; j < 6; ++j)
        xv[j] = *(const float*)(xsb + (off[j] + laneoff));
    const float* pl = l1 + (t * 36 + n1) * 64;
    return contract64<PRE>(pl, xv[0], xv[1], xv[2], xv[3], xv[4], xv[5]);
}

// Level-2 node: its 6 inputs are level-1 nodes (recomputed on demand —
// exactly 36 L1 evals total either way, so no intermediate storage needed).
template<bool PRE>
__device__ __forceinline__ float eval_l2(int t, int n2,
                                         const int* __restrict__ map2,
                                         const int* __restrict__ idx1,
                                         const float* __restrict__ l1,
                                         const float* __restrict__ l2,
                                         const char* __restrict__ xsb,
                                         int laneoff) {
    const int* m2 = map2 + (t * 6 + n2) * 6;
    float xv[6];
#pragma unroll
    for (int j = 0; j < 6; ++j) {
        int n1 = __builtin_amdgcn_readfirstlane(m2[j]);
        xv[j] = eval_l1<PRE>(t, n1, idx1, l1, xsb, laneoff);
    }
    const float* pl = l2 + (t * 6 + n2) * 64;
    return contract64<PRE>(pl, xv[0], xv[1], xv[2], xv[3], xv[4], xv[5]);
}

template<bool PRE>
__global__ __launch_bounds__(TILE_POS)
void lutconv_kernel(const float* __restrict__ x,
                    const int* __restrict__ map2,
                    const int* __restrict__ map3,
                    const int* __restrict__ idx1,
                    const float* __restrict__ l1,
                    const float* __restrict__ l2,
                    const float* __restrict__ l3,
                    float* __restrict__ out) {
    __shared__ float xs[XTILE_FLOATS];

    const int tid = threadIdx.x;
    const int bid = blockIdx.x;
    // grid = B_ * NTILES * TGROUPS
    const int tg   = bid % TGROUPS;
    const int rest = bid / TGROUPS;
    const int tile = rest % NTILES;
    const int b    = rest / NTILES;

    // ---- Stage x tile: rows [tile*TH, tile*TH+INROWS) of all 32 channels ----
    {
        const float4* src = (const float4*)(x + (size_t)b * CIN * H_ * W_);
        float4* dst = (float4*)xs;
        const int r0x7 = tile * TH * (W_ / 4);  // row offset in float4 units
#pragma unroll
        for (int k = 0; k < XTILE_FLOATS / 4 / TILE_POS; ++k) {  // 14 iters
            int i   = k * TILE_POS + tid;
            int c   = i / (INROWS * (W_ / 4));           // /84
            int rem = i - c * (INROWS * (W_ / 4));
            dst[i] = src[c * (H_ * (W_ / 4)) + r0x7 + rem];
        }
    }
    __syncthreads();

    const int lrow = tid / OW_;
    const int lcol = tid - lrow * OW_;
    const int laneoff = (lrow * W_ + lcol) * 4;   // byte offset of patch origin
    const char* xsb = (const char*)xs;

    const int t0 = tg * NT;
    const int oh = tile * TH + lrow;
    float* outp = out + (((size_t)b * COUT) * OH_ + oh) * OW_ + lcol;

#pragma unroll 1
    for (int tt = 0; tt < NT; ++tt) {
        const int t = t0 + tt;
        // Level 3: root gathers 6 level-2 nodes via map3 chain.
        const int* m3 = map3 + t * 6;
        float xv[6];
#pragma unroll
        for (int j = 0; j < 6; ++j) {
            int n2 = __builtin_amdgcn_readfirstlane(m3[j]);
            xv[j] = eval_l2<PRE>(t, n2, map2, idx1, l1, l2, xsb, laneoff);
        }
        const float* pl = l3 + t * 64;
        float r = contract64<PRE>(pl, xv[0], xv[1], xv[2], xv[3], xv[4], xv[5]);
        outp[(size_t)t * (OH_ * OW_)] = r;
    }
}

// ---- Setup kernels (run every launch; ws is re-poisoned each call) ----
__global__ void prep_a1(const int* __restrict__ map1, int* __restrict__ a1) {
    int i = blockIdx.x * 256 + threadIdx.x;
    if (i < COUT * 36 * 6) {
        int m  = map1[i];
        int c  = m / 25;
        int r  = m - 25 * c;
        int kh = r / 5;
        int kw = r - 5 * kh;
        a1[i] = (c * (INROWS * W_) + kh * W_ + kw) * 4;  // byte offset in x tile
    }
}

__global__ void prep_pl(const float* __restrict__ lut, float* __restrict__ pl, int npairs) {
    int i = blockIdx.x * 256 + threadIdx.x;
    if (i < npairs) {
        float b = lut[2*i];
        float a = lut[2*i+1];
        pl[2*i]   = b;
        pl[2*i+1] = a - b;
    }
}

extern "C" void kernel_launch(void* const* d_in, const int* in_sizes, int n_in,
                              void* d_out, int out_size, void* d_ws, size_t ws_size,
                              hipStream_t stream) {
    const float* x    = (const float*)d_in[0];
    const int*   map1 = (const int*)d_in[1];
    const float* lut1 = (const float*)d_in[2];
    const int*   map2 = (const int*)d_in[3];
    const float* lut2 = (const float*)d_in[4];
    const int*   map3 = (const int*)d_in[5];
    const float* lut3 = (const float*)d_in[6];
    float* out = (float*)d_out;

    dim3 grid(B_ * NTILES * TGROUPS);
    dim3 block(TILE_POS);

    if (ws_size >= (size_t)WS_NEEDED) {
        char* w = (char*)d_ws;
        int*   a1  = (int*)w;
        float* pl1 = (float*)(w + A1_BYTES);
        float* pl2 = (float*)(w + A1_BYTES + PL1_BYTES);
        float* pl3 = (float*)(w + A1_BYTES + PL1_BYTES + PL2_BYTES);

        prep_a1<<<(COUT*36*6 + 255)/256, 256, 0, stream>>>(map1, a1);
        prep_pl<<<(COUT*36*32 + 255)/256, 256, 0, stream>>>(lut1, pl1, COUT*36*32);
        prep_pl<<<(COUT*6*32  + 255)/256, 256, 0, stream>>>(lut2, pl2, COUT*6*32);
        prep_pl<<<(COUT*1*32  + 255)/256, 256, 0, stream>>>(lut3, pl3, COUT*1*32);

        lutconv_kernel<true><<<grid, block, 0, stream>>>(
            x, map2, map3, a1, pl1, pl2, pl3, out);
    } else {
        lutconv_kernel<false><<<grid, block, 0, stream>>>(
            x, map2, map3, map1, lut1, lut2, lut3, out);
    }
}

// Round 2
// 663.521 us; speedup vs baseline: 1.2033x; 1.2033x over previous
//
#include <hip/hip_runtime.h>

// Problem constants
#define B_      64
#define CIN     32
#define H_      28
#define W_      28
#define K_      5
#define OH_     24
#define OW_     24
#define COUT    128
#define NPOS    (OH_ * OW_)          // 576
#define IN_SIZE (CIN * K_ * K_)      // 800
#define XSTRIDE (CIN * H_ * W_)      // 25088 floats per image
#define BHALF   32                   // position-pair partner: (b, b+32)

// Mapping
#define NT      8                    // trees per block (loop)
#define TGROUPS (COUT / NT)          // 16
#define BLOCK   256
#define NPAIRU  (BHALF * NPOS)       // 18432 pair-units
#define UBLOCKS (NPAIRU / BLOCK)     // 72

// Workspace layout (bytes) — same as previous round
#define A1_BYTES  (COUT * 36 * 6 * 4)
#define PL1_BYTES (COUT * 36 * 64 * 4)
#define PL2_BYTES (COUT * 6 * 64 * 4)
#define PL3_BYTES (COUT * 1 * 64 * 4)
#define WS_NEEDED (A1_BYTES + PL1_BYTES + PL2_BYTES + PL3_BYTES)

typedef float f2 __attribute__((ext_vector_type(2)));

// Packed lerp: a + x*(b-a). __builtin_elementwise_fma on <2 x float>
// selects v_pk_fma_f32 on gfx90a+ (both halves share the same association
// as the scalar version, so rounding matches the accepted round-1 kernel).
__device__ __forceinline__ f2 lerp2(f2 a, f2 b, f2 x) {
    return __builtin_elementwise_fma(x, b - a, a);
}

__device__ __forceinline__ f2 clamp2(f2 v) {
    f2 r;
    r.x = __builtin_amdgcn_fmed3f(v.x, 0.0f, 1.0f);
    r.y = __builtin_amdgcn_fmed3f(v.y, 0.0f, 1.0f);
    return r;
}

// DFS contraction over 64 LUT entries (depth-first keeps ~7 pairs live).
// Entry-pair a covers lut entries (2a, 2a+1); leaves lerp by xs[5] (LSB var).
// PRE: L holds (base, delta) pairs; !PRE: raw lut values.
template<bool PRE, int M>
struct Rec {
    static __device__ __forceinline__ f2 go(const float* __restrict__ L, int a0,
                                            const f2* xs) {
        f2 lo = Rec<PRE, M - 1>::go(L, a0, xs);
        f2 hi = Rec<PRE, M - 1>::go(L, a0 + (1 << (M - 2)), xs);
        return lerp2(lo, hi, xs[6 - M]);
    }
};
template<bool PRE>
struct Rec<PRE, 1> {
    static __device__ __forceinline__ f2 go(const float* __restrict__ L, int a0,
                                            const f2* xs) {
        // Scalar leaf: coefficients are wave-uniform scalars (SGPRs); the
        // 1-SGPR-per-VALU rule makes a packed form need extra movs anyway.
        // Compiler CSEs the single s->v mov across both halves: ~3 instr.
        float b = L[2 * a0];
        float q = L[2 * a0 + 1];
        float d = PRE ? q : (q - b);
        f2 r;
        r.x = fmaf(xs[5].x, d, b);
        r.y = fmaf(xs[5].y, d, b);
        return r;
    }
};

template<bool PRE>
__device__ __forceinline__ f2 contract64p(const float* __restrict__ L, const f2* xs) {
    return clamp2(Rec<PRE, 6>::go(L, 0, xs));
}

// Level-1 node: 6 x-gathers straight from global (uniform offset + lane pixel).
template<bool PRE>
__device__ __forceinline__ f2 eval_l1(int t, int n1,
                                      const int* __restrict__ idx1,
                                      const float* __restrict__ l1,
                                      const float* __restrict__ xb0,
                                      const float* __restrict__ xb1,
                                      int lane_lin) {
    const int base = (t * 36 + n1) * 6;
    f2 xs[6];
#pragma unroll
    for (int j = 0; j < 6; ++j) {
        int m = idx1[base + j];
        int off;
        if (PRE) {
            off = m;                       // precomputed element offset
        } else {
            int c  = m / 25;
            int r  = m - 25 * c;
            int kh = r / 5;
            int kw = r - 5 * kh;
            off = c * (H_ * W_) + kh * W_ + kw;
        }
        off = __builtin_amdgcn_readfirstlane(off);
        f2 v;
        v.x = xb0[off + lane_lin];
        v.y = xb1[off + lane_lin];
        xs[j] = v;
    }
    return contract64p<PRE>(l1 + (t * 36 + n1) * 64, xs);
}

template<bool PRE>
__device__ __forceinline__ f2 eval_l2(int t, int n2,
                                      const int* __restrict__ map2,
                                      const int* __restrict__ idx1,
                                      const float* __restrict__ l1,
                                      const float* __restrict__ l2,
                                      const float* __restrict__ xb0,
                                      const float* __restrict__ xb1,
                                      int lane_lin) {
    const int* m2 = map2 + (t * 6 + n2) * 6;
    f2 xs[6];
#pragma unroll
    for (int j = 0; j < 6; ++j) {
        int n1 = __builtin_amdgcn_readfirstlane(m2[j]);
        xs[j] = eval_l1<PRE>(t, n1, idx1, l1, xb0, xb1, lane_lin);
    }
    return contract64p<PRE>(l2 + (t * 6 + n2) * 64, xs);
}

template<bool PRE>
__global__ __launch_bounds__(BLOCK, 4)
void lutconv_pk(const float* __restrict__ x,
                const int* __restrict__ map2,
                const int* __restrict__ map3,
                const int* __restrict__ idx1,
                const float* __restrict__ l1,
                const float* __restrict__ l2,
                const float* __restrict__ l3,
                float* __restrict__ out) {
    const int bid = blockIdx.x;
    const int tg  = bid % TGROUPS;       // tree group (fast dim)
    const int u   = bid / TGROUPS;       // pair-unit chunk, 0..71
    const int g   = u * BLOCK + threadIdx.x;   // 0..18431
    const int bp  = g / NPOS;            // 0..31 -> images (bp, bp+32)
    const int pos = g - bp * NPOS;       // 0..575
    const int oh  = pos / OW_;
    const int ow  = pos - oh * OW_;
    const int lane_lin = oh * W_ + ow;   // pixel offset of patch origin

    const float* xb0 = x + (size_t)bp * XSTRIDE;
    const float* xb1 = xb0 + (size_t)BHALF * XSTRIDE;
    float* o0 = out + (size_t)bp * COUT * NPOS + pos;
    float* o1 = o0 + (size_t)BHALF * COUT * NPOS;

    const int t0 = tg * NT;
#pragma unroll 1
    for (int tt = 0; tt < NT; ++tt) {
        const int t = t0 + tt;
        const int* m3 = map3 + t * 6;
        f2 xs[6];
#pragma unroll
        for (int j = 0; j < 6; ++j) {
            int n2 = __builtin_amdgcn_readfirstlane(m3[j]);
            xs[j] = eval_l2<PRE>(t, n2, map2, idx1, l1, l2, xb0, xb1, lane_lin);
        }
        f2 r = contract64p<PRE>(l3 + t * 64, xs);
        o0[(size_t)t * NPOS] = r.x;
        o1[(size_t)t * NPOS] = r.y;
    }
}

// ---- Setup kernels (run every launch; ws is re-poisoned each call) ----
__global__ void prep_a1(const int* __restrict__ map1, int* __restrict__ a1) {
    int i = blockIdx.x * 256 + threadIdx.x;
    if (i < COUT * 36 * 6) {
        int m  = map1[i];
        int c  = m / 25;
        int r  = m - 25 * c;
        int kh = r / 5;
        int kw = r - 5 * kh;
        a1[i] = c * (H_ * W_) + kh * W_ + kw;   // element offset in full image
    }
}

__global__ void prep_pl(const float* __restrict__ lut, float* __restrict__ pl, int npairs) {
    int i = blockIdx.x * 256 + threadIdx.x;
    if (i < npairs) {
        float b = lut[2 * i];
        float a = lut[2 * i + 1];
        pl[2 * i]     = b;
        pl[2 * i + 1] = a - b;
    }
}

extern "C" void kernel_launch(void* const* d_in, const int* in_sizes, int n_in,
                              void* d_out, int out_size, void* d_ws, size_t ws_size,
                              hipStream_t stream) {
    const float* x    = (const float*)d_in[0];
    const int*   map1 = (const int*)d_in[1];
    const float* lut1 = (const float*)d_in[2];
    const int*   map2 = (const int*)d_in[3];
    const float* lut2 = (const float*)d_in[4];
    const int*   map3 = (const int*)d_in[5];
    const float* lut3 = (const float*)d_in[6];
    float* out = (float*)d_out;

    dim3 grid(UBLOCKS * TGROUPS);
    dim3 block(BLOCK);

    if (ws_size >= (size_t)WS_NEEDED) {
        char* w = (char*)d_ws;
        int*   a1  = (int*)w;
        float* pl1 = (float*)(w + A1_BYTES);
        float* pl2 = (float*)(w + A1_BYTES + PL1_BYTES);
        float* pl3 = (float*)(w + A1_BYTES + PL1_BYTES + PL2_BYTES);

        prep_a1<<<(COUT*36*6 + 255)/256, 256, 0, stream>>>(map1, a1);
        prep_pl<<<(COUT*36*32 + 255)/256, 256, 0, stream>>>(lut1, pl1, COUT*36*32);
        prep_pl<<<(COUT*6*32  + 255)/256, 256, 0, stream>>>(lut2, pl2, COUT*6*32);
        prep_pl<<<(COUT*1*32  + 255)/256, 256, 0, stream>>>(lut3, pl3, COUT*1*32);

        lutconv_pk<true><<<grid, block, 0, stream>>>(
            x, map2, map3, a1, pl1, pl2, pl3, out);
    } else {
        lutconv_pk<false><<<grid, block, 0, stream>>>(
            x, map2, map3, map1, lut1, lut2, lut3, out);
    }
}